// Round 9
// baseline (115.438 us; speedup 1.0000x reference)
//
#include <hip/hip_runtime.h>

#define DD 160
#define HH 160
#define WW 160
#define VOL (DD * HH * WW)   // per-batch volume = 4,096,000
#define PLANE (HH * WW)      // 25,600
#define NB 2

// pass 1a: D-sum streaming (4 columns/thread, add/sub window, no ring)
#define CH 20                // d-centers per block
#define NDSP (DD / CH)       // 8
#define DSBLK (PLANE / 1024) // 25 quad-tiles (256 thr * 4 cols)
#define NDSUM (DSBLK * NDSP * NB)  // 400 blocks

// pass 1b: grad
#define GCHD 20
#define GBLK (NB * 3 * (DD / GCHD) * HH * (WW / 4) / 256)   // 1200 blocks

// pass 2: WH + cc
#define HT 16
#define HS (HT + 8)          // 24 staged rows
#define LDWH 168             // LDS row stride (halves), 336B
#define WHBLK ((HH / HT) * DD * NB)   // 3200

typedef _Float16 h8 __attribute__((ext_vector_type(8)));
typedef _Float16 h4 __attribute__((ext_vector_type(4)));

// ---------------------------------------------------------------------------
// Pass 1 (merged): blocks [0, NDSUM): D-direction box sums of the 5 moment
// fields via add/sub sliding window on raw m,f (re-read of d-4 is L1/L2-hot,
// raw volumes are L3-resident). 4 columns/thread: float4 loads, h4 stores.
// Blocks [NDSUM, NDSUM+GBLK): flow L1-gradient reduction.
// ---------------------------------------------------------------------------
__global__ __launch_bounds__(256) void stream_pass(const float* __restrict__ mv,
                                                   const float* __restrict__ fx,
                                                   const float* __restrict__ fl,
                                                   _Float16* __restrict__ fields,
                                                   float* __restrict__ pg) {
    const int bx  = blockIdx.x;
    const int tid = threadIdx.x;

    if (bx < NDSUM) {
        const int qt  = bx % DSBLK;          // quad-tile
        const int rem = bx / DSBLK;
        const int dsp = rem % NDSP;
        const int b   = rem / NDSP;
        const int hw  = (qt * 256 + tid) * 4;   // 0..25596
        const int c0  = dsp * CH;
        const int cend = c0 + CH;

        const float* pm = mv + (size_t)b * VOL + hw;
        const float* pf = fx + (size_t)b * VOL + hw;
        _Float16*    fb = fields + (size_t)b * 5 * VOL + hw;

        float4 s0 = {0,0,0,0}, s1 = {0,0,0,0}, s2 = {0,0,0,0},
               s3 = {0,0,0,0}, s4 = {0,0,0,0};

#define ACC4(m4, f4, sgn)                                              \
        s0.x sgn m4.x; s0.y sgn m4.y; s0.z sgn m4.z; s0.w sgn m4.w;    \
        s1.x sgn f4.x; s1.y sgn f4.y; s1.z sgn f4.z; s1.w sgn f4.w;    \
        s2.x sgn m4.x * m4.x; s2.y sgn m4.y * m4.y;                    \
        s2.z sgn m4.z * m4.z; s2.w sgn m4.w * m4.w;                    \
        s3.x sgn f4.x * f4.x; s3.y sgn f4.y * f4.y;                    \
        s3.z sgn f4.z * f4.z; s3.w sgn f4.w * f4.w;                    \
        s4.x sgn m4.x * f4.x; s4.y sgn m4.y * f4.y;                    \
        s4.z sgn m4.z * f4.z; s4.w sgn m4.w * f4.w;

        {   // warm-up: planes [c0-4, c0+4] clipped
            int lo = c0 - 4 > 0 ? c0 - 4 : 0;
            int hi = c0 + 4 < DD - 1 ? c0 + 4 : DD - 1;
            for (int dd = lo; dd <= hi; ++dd) {
                float4 m4 = *(const float4*)(pm + (size_t)dd * PLANE);
                float4 f4 = *(const float4*)(pf + (size_t)dd * PLANE);
                ACC4(m4, f4, +=)
            }
        }

        for (int d = c0; d < cend; ++d) {
            _Float16* o = fb + (size_t)d * PLANE;
            h4 t;
            t.x = (_Float16)s0.x; t.y = (_Float16)s0.y; t.z = (_Float16)s0.z; t.w = (_Float16)s0.w;
            *(h4*)(o + 0 * (size_t)VOL) = t;
            t.x = (_Float16)s1.x; t.y = (_Float16)s1.y; t.z = (_Float16)s1.z; t.w = (_Float16)s1.w;
            *(h4*)(o + 1 * (size_t)VOL) = t;
            t.x = (_Float16)s2.x; t.y = (_Float16)s2.y; t.z = (_Float16)s2.z; t.w = (_Float16)s2.w;
            *(h4*)(o + 2 * (size_t)VOL) = t;
            t.x = (_Float16)s3.x; t.y = (_Float16)s3.y; t.z = (_Float16)s3.z; t.w = (_Float16)s3.w;
            *(h4*)(o + 3 * (size_t)VOL) = t;
            t.x = (_Float16)s4.x; t.y = (_Float16)s4.y; t.z = (_Float16)s4.z; t.w = (_Float16)s4.w;
            *(h4*)(o + 4 * (size_t)VOL) = t;

            if (d + 1 < cend) {
                if (d + 5 < DD) {
                    float4 m4 = *(const float4*)(pm + (size_t)(d + 5) * PLANE);
                    float4 f4 = *(const float4*)(pf + (size_t)(d + 5) * PLANE);
                    ACC4(m4, f4, +=)
                }
                if (d - 4 >= 0) {
                    float4 m4 = *(const float4*)(pm + (size_t)(d - 4) * PLANE);
                    float4 f4 = *(const float4*)(pf + (size_t)(d - 4) * PLANE);
                    ACC4(m4, f4, -=)
                }
            }
        }
#undef ACC4
        return;
    }

    // ---- grad: L1 forward diffs on flow, d-walking float4 chunks ----
    const int gid = (bx - NDSUM) * 256 + tid;    // 0..307199
    const int w4  = gid % 40;
    int t = gid / 40;
    const int h  = t % HH;  t /= HH;
    const int dc = t % (DD / GCHD); t /= (DD / GCHD);
    const int bc = t;                            // 0..5
    const int d0 = dc * GCHD;
    const int w  = w4 * 4;

    const float* base = fl + (size_t)bc * VOL;
    float acc = 0.f;
    float4 v = *(const float4*)(base + ((size_t)d0 * HH + h) * WW + w);
    for (int d = d0; d < d0 + GCHD; ++d) {
        const float* pd = base + ((size_t)d * HH + h) * WW + w;
        float4 vn = v;
        if (d < DD - 1) {
            vn = *(const float4*)(pd + PLANE);
            acc += fabsf(vn.x - v.x) + fabsf(vn.y - v.y) +
                   fabsf(vn.z - v.z) + fabsf(vn.w - v.w);
        }
        if (h < HH - 1) {
            float4 vh = *(const float4*)(pd + WW);
            acc += fabsf(vh.x - v.x) + fabsf(vh.y - v.y) +
                   fabsf(vh.z - v.z) + fabsf(vh.w - v.w);
        }
        acc += fabsf(v.y - v.x) + fabsf(v.z - v.y) + fabsf(v.w - v.z);
        if (w < WW - 4) acc += fabsf(pd[4] - v.w);
        v = vn;
    }

    for (int o = 32; o > 0; o >>= 1) acc += __shfl_down(acc, o, 64);
    __shared__ float red[4];
    int lane = tid & 63, wid = tid >> 6;
    if (lane == 0) red[wid] = acc;
    __syncthreads();
    if (tid == 0) pg[bx - NDSUM] = red[0] + red[1] + red[2] + red[3];
}

// ---------------------------------------------------------------------------
// Pass 2: W+H box sums of the 5 D-summed fields + per-voxel cc + reduction.
// Block: 512 thr, output tile 16h x 160w at one (d, b). Grid (10, 160, 2).
// ---------------------------------------------------------------------------
__global__ __launch_bounds__(512, 6) void ncc_whcc(const _Float16* __restrict__ fields,
                                                   float* __restrict__ partial) {
    __shared__ _Float16 ws[5][HS][LDWH];
    __shared__ float red[8];

    const int hx  = blockIdx.x;        // 0..9
    const int d   = blockIdx.y;        // 0..159
    const int b   = blockIdx.z;        // 0..1
    const int h0  = hx * HT;
    const int tid = threadIdx.x;

    if (tid < 480) {
        const int r  = tid / 20;       // 0..23 staged row
        const int s  = tid - r * 20;   // 0..19 octet
        const int h  = h0 - 4 + r;
        const int w0 = 8 * s;
        const bool rowok = (unsigned)h < (unsigned)HH;

#pragma unroll
        for (int f = 0; f < 5; ++f) {
            float v[16];
#pragma unroll
            for (int i = 0; i < 16; ++i) v[i] = 0.f;
            if (rowok) {
                const _Float16* fr = fields + (size_t)(b * 5 + f) * VOL
                                            + ((size_t)d * HH + h) * WW;
                if (s > 0) {
                    h4 a = *(const h4*)(fr + w0 - 4);
                    v[0] = (float)a.x; v[1] = (float)a.y; v[2] = (float)a.z; v[3] = (float)a.w;
                }
                h4 a1 = *(const h4*)(fr + w0);
                v[4] = (float)a1.x; v[5] = (float)a1.y; v[6] = (float)a1.z; v[7] = (float)a1.w;
                h4 a2 = *(const h4*)(fr + w0 + 4);
                v[8] = (float)a2.x; v[9] = (float)a2.y; v[10] = (float)a2.z; v[11] = (float)a2.w;
                if (s < 19) {
                    h4 a3 = *(const h4*)(fr + w0 + 8);
                    v[12] = (float)a3.x; v[13] = (float)a3.y; v[14] = (float)a3.z; v[15] = (float)a3.w;
                }
            }
            float o[8];
            float sum = 0.f;
#pragma unroll
            for (int i = 0; i < 9; ++i) sum += v[i];
            o[0] = sum;
#pragma unroll
            for (int k = 1; k < 8; ++k) {
                sum += v[k + 8] - v[k - 1];
                o[k] = sum;
            }
            h8 pk;
#pragma unroll
            for (int j = 0; j < 8; ++j) pk[j] = (_Float16)o[j];
            *(h8*)&ws[f][r][w0] = pk;
        }
    }
    __syncthreads();

    float acc = 0.f;
    if (tid < 320) {
        const int ro  = tid / 20;      // 0..15 output row
        const int oct = tid - ro * 20; // 0..19
        const int w   = 8 * oct;

        float s0[8], s1[8], s2[8], s3[8], s4[8];
#pragma unroll
        for (int j = 0; j < 8; ++j) { s0[j]=0.f; s1[j]=0.f; s2[j]=0.f; s3[j]=0.f; s4[j]=0.f; }
#pragma unroll
        for (int t = 0; t < 9; ++t) {
            h8 v0 = *(const h8*)&ws[0][ro + t][w];
            h8 v1 = *(const h8*)&ws[1][ro + t][w];
            h8 v2 = *(const h8*)&ws[2][ro + t][w];
            h8 v3 = *(const h8*)&ws[3][ro + t][w];
            h8 v4 = *(const h8*)&ws[4][ro + t][w];
#pragma unroll
            for (int j = 0; j < 8; ++j) {
                s0[j] += (float)v0[j]; s1[j] += (float)v1[j];
                s2[j] += (float)v2[j]; s3[j] += (float)v3[j];
                s4[j] += (float)v4[j];
            }
        }
        const float inv_win = 1.0f / 729.0f;
#pragma unroll
        for (int j = 0; j < 8; ++j) {
            float cross = fmaf(-(s0[j] * s1[j]), inv_win, s4[j]);
            float pv = fmaxf(fmaf(-(s0[j] * s0[j]), inv_win, s2[j]), 0.f);
            float tv = fmaxf(fmaf(-(s1[j] * s1[j]), inv_win, s3[j]), 0.f);
            float cc = cross * cross / (pv * tv + 0.001f);
            acc += fminf(fmaxf(cc, 0.f), 1.f);
        }
    }

    for (int o = 32; o > 0; o >>= 1) acc += __shfl_down(acc, o, 64);
    int lane = tid & 63, wid = tid >> 6;
    if (lane == 0) red[wid] = acc;
    __syncthreads();
    if (tid == 0) {
        float r8 = 0.f;
#pragma unroll
        for (int i = 0; i < 8; ++i) r8 += red[i];
        partial[((size_t)b * DD + d) * (HH / HT) + hx] = r8;
    }
}

// ---------------------------------------------------------------------------
// Pass 3: final deterministic reduction of partials -> scalar loss
// ---------------------------------------------------------------------------
__global__ __launch_bounds__(256) void finalize(const float* __restrict__ pcc, int ncc,
                                                const float* __restrict__ pg, int ng,
                                                float* __restrict__ out) {
    __shared__ float red[4];
    int lane = threadIdx.x & 63, wid = threadIdx.x >> 6;

    float a = 0.f;
    for (int i = threadIdx.x; i < ncc; i += 256) a += pcc[i];
    for (int o = 32; o > 0; o >>= 1) a += __shfl_down(a, o, 64);
    if (lane == 0) red[wid] = a;
    __syncthreads();
    float asum = red[0] + red[1] + red[2] + red[3];
    __syncthreads();

    float g = 0.f;
    for (int i = threadIdx.x; i < ng; i += 256) g += pg[i];
    for (int o = 32; o > 0; o >>= 1) g += __shfl_down(g, o, 64);
    if (lane == 0) red[wid] = g;
    __syncthreads();
    float gsum = red[0] + red[1] + red[2] + red[3];

    if (threadIdx.x == 0) {
        float sim = 1.0f - asum / 8192000.0f;          // mean over (2,1,160,160,160)
        float reg = gsum / 73267200.0f;                // 3 * (2*3*159*160*160)
        out[0] = sim + reg;
    }
}

// ---------------------------------------------------------------------------
extern "C" void kernel_launch(void* const* d_in, const int* in_sizes, int n_in,
                              void* d_out, int out_size, void* d_ws, size_t ws_size,
                              hipStream_t stream) {
    const float* moved  = (const float*)d_in[0];
    const float* fixedp = (const float*)d_in[1];
    const float* flow   = (const float*)d_in[2];
    float* out = (float*)d_out;

    _Float16* fields = (_Float16*)d_ws;                   // NB*5*VOL fp16 (81.9 MB)
    float* pcc = (float*)(fields + (size_t)NB * 5 * VOL); // WHBLK floats
    float* pg  = pcc + WHBLK;                             // GBLK floats

    stream_pass<<<NDSUM + GBLK, 256, 0, stream>>>(moved, fixedp, flow, fields, pg);
    ncc_whcc<<<dim3(HH / HT, DD, NB), 512, 0, stream>>>(fields, pcc);
    finalize<<<1, 256, 0, stream>>>(pcc, WHBLK, pg, GBLK, out);
}